// Round 11
// baseline (207.626 us; speedup 1.0000x reference)
//
#include <hip/hip_runtime.h>
#include <cstdint>

#define D_MODEL 1024
#define N_HEADS 16
#define D_K     64
#define BATCH   2
#define SEQ     2048
#define TOKENS  (BATCH * SEQ)
#define LN_EPS  1e-5f
// 1/sqrt(D_K) * log2(e), folded into Q so softmax uses exp2 directly
#define QSCALE  0.18033688011112042f

typedef __bf16 bf16x8 __attribute__((ext_vector_type(8)));
typedef float  floatx4  __attribute__((ext_vector_type(4)));
typedef float  floatx16 __attribute__((ext_vector_type(16)));

__device__ __forceinline__ unsigned short f2bf(float f) {
  union { float f; unsigned u; } v; v.f = f;
  unsigned r = v.u + 0x7fffu + ((v.u >> 16) & 1u);
  return (unsigned short)(r >> 16);
}
// pack two f32 -> two bf16 (truncate) in ONE v_perm_b32
__device__ __forceinline__ unsigned pk2bf(float hi, float lo) {
  union { float f; unsigned u; } a, b;
  a.f = hi; b.f = lo;
  return __builtin_amdgcn_perm(a.u, b.u, 0x07060302u);
}

// async global -> LDS, 16 B per lane; LDS dest = wave-uniform base + lane*16
__device__ __forceinline__ void cp16(void* lds, const void* g) {
  __builtin_amdgcn_global_load_lds(
      (__attribute__((address_space(1))) void*)g,
      (__attribute__((address_space(3))) void*)lds, 16, 0, 0);
}

// ---------------- prep: weight fp32->bf16 (blocks 0..4095) + LN (4096..8191)
__global__ __launch_bounds__(256) void prep_kernel(
    const float* __restrict__ h, const float* __restrict__ w0,
    const float* __restrict__ w1, const float* __restrict__ w2,
    const float* __restrict__ w3, const float* __restrict__ lw,
    const float* __restrict__ lb, unsigned short* __restrict__ Wcat,
    unsigned short* __restrict__ hn) {
  if (blockIdx.x < 4096) {
    int wsel = blockIdx.x >> 10;
    const float* s = (wsel == 0) ? w0 : (wsel == 1) ? w1 : (wsel == 2) ? w2 : w3;
    unsigned short* d = Wcat + ((size_t)wsel << 20);
    int i = ((blockIdx.x & 1023) << 8) + threadIdx.x;
    float4 v = reinterpret_cast<const float4*>(s)[i];
    ushort4 o;
    o.x = f2bf(v.x); o.y = f2bf(v.y); o.z = f2bf(v.z); o.w = f2bf(v.w);
    reinterpret_cast<ushort4*>(d)[i] = o;
    return;
  }
  int row = blockIdx.x - 4096;
  const float* x = h + (size_t)row * D_MODEL;
  float4 v = reinterpret_cast<const float4*>(x)[threadIdx.x];
  float s  = v.x + v.y + v.z + v.w;
  float s2 = v.x * v.x + v.y * v.y + v.z * v.z + v.w * v.w;
  for (int m = 1; m < 64; m <<= 1) {
    s  += __shfl_xor(s, m);
    s2 += __shfl_xor(s2, m);
  }
  __shared__ float ls[4], ls2[4];
  int wave = threadIdx.x >> 6;
  if ((threadIdx.x & 63) == 0) { ls[wave] = s; ls2[wave] = s2; }
  __syncthreads();
  s  = ls[0] + ls[1] + ls[2] + ls[3];
  s2 = ls2[0] + ls2[1] + ls2[2] + ls2[3];
  float mu  = s * (1.0f / D_MODEL);
  float var = s2 * (1.0f / D_MODEL) - mu * mu;
  float rs  = rsqrtf(var + LN_EPS);
  float4 wv = reinterpret_cast<const float4*>(lw)[threadIdx.x];
  float4 bv = reinterpret_cast<const float4*>(lb)[threadIdx.x];
  ushort4 o;
  o.x = f2bf((v.x - mu) * rs * wv.x + bv.x);
  o.y = f2bf((v.y - mu) * rs * wv.y + bv.y);
  o.z = f2bf((v.z - mu) * rs * wv.z + bv.z);
  o.w = f2bf((v.w - mu) * rs * wv.w + bv.w);
  reinterpret_cast<ushort4*>(hn + (size_t)row * D_MODEL)[threadIdx.x] = o;
}

// ---------------- fused QKV GEMM: [4096,1024] @ [3072,1024]^T -------------
__global__ __launch_bounds__(256) void gemm_qkv_kernel(
    const unsigned short* __restrict__ A, const unsigned short* __restrict__ Wcat,
    const float* __restrict__ bq, const float* __restrict__ bk,
    const float* __restrict__ bv,
    unsigned short* __restrict__ QK, unsigned short* __restrict__ VtG) {
  __shared__ unsigned short As[128 * 64];
  __shared__ unsigned short Bs[128 * 64];

  const int tid  = threadIdx.x;
  const int w    = tid >> 6;
  const int lane = tid & 63;
  const int l15  = lane & 15;
  const int quad = lane >> 4;
  const int sw   = l15 & 7;
  const int wm = (w >> 1) * 64;
  const int wn = (w & 1) * 64;
  const int bm = blockIdx.y * 128;
  const int bn = blockIdx.x * 128;

  const int srow = tid >> 3;                        // 0..31
  const int swzc = (((tid & 7) ^ (srow & 7)) * 8);  // swizzled source col
  const unsigned short* ga = A    + (size_t)(bm + srow) * 1024 + swzc;
  const unsigned short* gb = Wcat + (size_t)(bn + srow) * 1024 + swzc;
  unsigned short* asl = As + w * 512;
  unsigned short* bsl = Bs + w * 512;

  floatx4 acc[4][4];
  for (int i = 0; i < 4; ++i)
    for (int j = 0; j < 4; ++j) acc[i][j] = {0.f, 0.f, 0.f, 0.f};

  for (int k0 = 0; k0 < 1024; k0 += 64) {
#pragma unroll
    for (int i = 0; i < 4; ++i) cp16(asl + i * 2048, ga + (size_t)i * 32 * 1024 + k0);
#pragma unroll
    for (int i = 0; i < 4; ++i) cp16(bsl + i * 2048, gb + (size_t)i * 32 * 1024 + k0);
    __syncthreads();
#pragma unroll
    for (int kb = 0; kb < 2; ++kb) {
      bf16x8 af[4], bfr[4];
#pragma unroll
      for (int mi = 0; mi < 4; ++mi)
        af[mi] = *reinterpret_cast<const bf16x8*>(
            As + (wm + mi * 16 + l15) * 64 + (((kb * 4 + quad) ^ sw) * 8));
#pragma unroll
      for (int ni = 0; ni < 4; ++ni)
        bfr[ni] = *reinterpret_cast<const bf16x8*>(
            Bs + (wn + ni * 16 + l15) * 64 + (((kb * 4 + quad) ^ sw) * 8));
#pragma unroll
      for (int mi = 0; mi < 4; ++mi)
#pragma unroll
        for (int ni = 0; ni < 4; ++ni)
          acc[mi][ni] = __builtin_amdgcn_mfma_f32_16x16x32_bf16(af[mi], bfr[ni], acc[mi][ni], 0, 0, 0);
    }
    __syncthreads();
  }

  const int wsel = blockIdx.x >> 3;  // uniform: 0=Q 1=K 2=V
  if (wsel == 0) {
#pragma unroll
    for (int mi = 0; mi < 4; ++mi)
#pragma unroll
      for (int ni = 0; ni < 4; ++ni) {
        int col = bn + wn + ni * 16 + l15;
        float bb = bq[col];
#pragma unroll
        for (int r = 0; r < 4; ++r) {
          int row = bm + wm + mi * 16 + quad * 4 + r;
          QK[(size_t)row * 2048 + col] = f2bf((acc[mi][ni][r] + bb) * QSCALE);
        }
      }
  } else if (wsel == 1) {
#pragma unroll
    for (int mi = 0; mi < 4; ++mi)
#pragma unroll
      for (int ni = 0; ni < 4; ++ni) {
        int col = bn + wn + ni * 16 + l15;
        float bb = bk[col - 1024];
#pragma unroll
        for (int r = 0; r < 4; ++r) {
          int row = bm + wm + mi * 16 + quad * 4 + r;
          QK[(size_t)row * 2048 + col] = f2bf(acc[mi][ni][r] + bb);
        }
      }
  } else {
#pragma unroll
    for (int mi = 0; mi < 4; ++mi)
#pragma unroll
      for (int ni = 0; ni < 4; ++ni) {
        int d = bn + wn + ni * 16 + l15 - 2048;
        float bb = bv[d];
        ushort4 o;
        o.x = f2bf(acc[mi][ni][0] + bb);
        o.y = f2bf(acc[mi][ni][1] + bb);
        o.z = f2bf(acc[mi][ni][2] + bb);
        o.w = f2bf(acc[mi][ni][3] + bb);
        int row0 = bm + wm + mi * 16 + quad * 4;
        *reinterpret_cast<ushort4*>(VtG + (size_t)d * 4096 + row0) = o;
      }
  }
}

// ---------------- output GEMM: Obuf @ Wo^T + bo + resid -> fp32 -----------
__global__ __launch_bounds__(256) void gemm_out_kernel(
    const unsigned short* __restrict__ A, const unsigned short* __restrict__ Bt,
    const float* __restrict__ bo, const float* __restrict__ resid,
    float* __restrict__ out) {
  __shared__ unsigned short As[128 * 64];
  __shared__ unsigned short Bs[64 * 64];

  const int tid  = threadIdx.x;
  const int w    = tid >> 6;
  const int lane = tid & 63;
  const int l15  = lane & 15;
  const int quad = lane >> 4;
  const int sw   = l15 & 7;
  const int wm = (w >> 1) * 64;
  const int wn = (w & 1) * 32;
  const int bm = blockIdx.y * 128;
  const int bn = blockIdx.x * 64;

  const int srow = tid >> 3;
  const int swzc = (((tid & 7) ^ (srow & 7)) * 8);
  const unsigned short* ga = A  + (size_t)(bm + srow) * 1024 + swzc;
  const unsigned short* gb = Bt + (size_t)(bn + srow) * 1024 + swzc;
  unsigned short* asl = As + w * 512;
  unsigned short* bsl = Bs + w * 512;

  floatx4 acc[4][2];
  for (int i = 0; i < 4; ++i)
    for (int j = 0; j < 2; ++j) acc[i][j] = {0.f, 0.f, 0.f, 0.f};

  for (int k0 = 0; k0 < 1024; k0 += 64) {
#pragma unroll
    for (int i = 0; i < 4; ++i) cp16(asl + i * 2048, ga + (size_t)i * 32 * 1024 + k0);
#pragma unroll
    for (int i = 0; i < 2; ++i) cp16(bsl + i * 2048, gb + (size_t)i * 32 * 1024 + k0);
    __syncthreads();
#pragma unroll
    for (int kb = 0; kb < 2; ++kb) {
      bf16x8 af[4], bfr[2];
#pragma unroll
      for (int mi = 0; mi < 4; ++mi)
        af[mi] = *reinterpret_cast<const bf16x8*>(
            As + (wm + mi * 16 + l15) * 64 + (((kb * 4 + quad) ^ sw) * 8));
#pragma unroll
      for (int ni = 0; ni < 2; ++ni)
        bfr[ni] = *reinterpret_cast<const bf16x8*>(
            Bs + (wn + ni * 16 + l15) * 64 + (((kb * 4 + quad) ^ sw) * 8));
#pragma unroll
      for (int mi = 0; mi < 4; ++mi)
#pragma unroll
        for (int ni = 0; ni < 2; ++ni)
          acc[mi][ni] = __builtin_amdgcn_mfma_f32_16x16x32_bf16(af[mi], bfr[ni], acc[mi][ni], 0, 0, 0);
    }
    __syncthreads();
  }

#pragma unroll
  for (int mi = 0; mi < 4; ++mi)
#pragma unroll
    for (int ni = 0; ni < 2; ++ni) {
      int col = bn + wn + ni * 16 + l15;
      float bb = bo[col];
#pragma unroll
      for (int r = 0; r < 4; ++r) {
        int row = bm + wm + mi * 16 + quad * 4 + r;
        size_t idx = (size_t)row * 1024 + col;
        out[idx] = acc[mi][ni][r] + bb + resid[idx];
      }
    }
}

// ---------------- flash attention: grid (H, S/64, B), 128 thr -------------
// R10's 32x32x16 register-P design, re-tiled for OCCUPANCY: 64 q per block,
// 2 waves x 32 q, grid 1024 -> 4 independent blocks/CU (same 8 waves/CU but
// 4 barrier groups instead of 2: one block's staging drain overlaps the
// others' compute — the m114 mechanism; this is what dbuf at 2 blocks/CU
// could not provide, so the double buffer is dropped). LDS = 32 KB.
__global__ __launch_bounds__(128) void attn_kernel(
    const unsigned short* __restrict__ QK, const unsigned short* __restrict__ VtG,
    unsigned short* __restrict__ O) {
  __shared__ unsigned short Ks[128 * 64];  // [key][d]  swizzled (16B gran ^row&7)
  __shared__ unsigned short Vs[64 * 128];  // [d][key]  swizzled

  const int tid  = threadIdx.x;            // 0..127
  const int w    = tid >> 6;               // 0..1
  const int lane = tid & 63;
  const int l31  = lane & 31;
  const int h    = lane >> 5;
  const int s7   = l31 & 7;

  const int hh = blockIdx.x, qt = blockIdx.y, bz = blockIdx.z;
  const int tq0  = bz * SEQ + qt * 64;
  const int hoff = hh * 64;

  // Q B-frags: n=q=lane&31, k = kd*16 + h*8 + j
  bf16x8 qf[4];
  {
    const unsigned short* qp =
        QK + (size_t)(tq0 + w * 32 + l31) * 2048 + hoff + h * 8;
#pragma unroll
    for (int kd = 0; kd < 4; ++kd)
      qf[kd] = *reinterpret_cast<const bf16x8*>(qp + kd * 16);
  }

  floatx16 oacc[2];
#pragma unroll
  for (int db = 0; db < 2; ++db)
#pragma unroll
    for (int r = 0; r < 16; ++r) oacc[db][r] = 0.f;
  float lsum = 0.f;

  // staging (128 thr): K 8 rounds x 16 rows; V 8 rounds x 8 d-rows.
  // invariant both sides: phys granule = logical ^ (row&7).
  const unsigned short* kg = QK + 1024 + hoff
      + (size_t)(bz * SEQ + (tid >> 3)) * 2048
      + (((tid & 7) ^ ((tid >> 3) & 7)) * 8);
  const unsigned short* vg = VtG
      + (size_t)(hoff + (tid >> 4)) * 4096 + bz * SEQ
      + (((tid & 15) ^ ((tid >> 4) & 7)) * 8);
  unsigned short* ksl = Ks + w * 512;
  unsigned short* vsl = Vs + w * 512;

  for (int kt = 0; kt < SEQ / 128; ++kt) {
    {
      const unsigned short* kgi = kg + (size_t)(kt * 128) * 2048;
      const unsigned short* vgi = vg + kt * 128;
#pragma unroll
      for (int i = 0; i < 8; ++i) cp16(ksl + i * 1024, kgi + (size_t)(i * 16) * 2048);
#pragma unroll
      for (int i = 0; i < 8; ++i) cp16(vsl + i * 1024, vgi + (size_t)(i * 8) * 4096);
    }
    __syncthreads();

    // S^T: 4 key-blocks of 32, K-dim 4 chunks of 16
    floatx16 ss[4];
#pragma unroll
    for (int kb = 0; kb < 4; ++kb)
#pragma unroll
      for (int r = 0; r < 16; ++r) ss[kb][r] = 0.f;
#pragma unroll
    for (int kb = 0; kb < 4; ++kb) {
      const unsigned short* krow = Ks + (kb * 32 + l31) * 64;
#pragma unroll
      for (int kd = 0; kd < 4; ++kd) {
        bf16x8 kf = *reinterpret_cast<const bf16x8*>(
            krow + (((kd * 2 + h) ^ s7) * 8));
        ss[kb] = __builtin_amdgcn_mfma_f32_32x32x16_bf16(kf, qf[kd], ss[kb], 0, 0, 0);
      }
    }

    // per key-block: exp2, row-sum, build PV B-frags in-register, PV MFMAs
#pragma unroll
    for (int kb = 0; kb < 4; ++kb) {
      float e[16];
      float bs = 0.f;
#pragma unroll
      for (int r = 0; r < 16; ++r) {
        e[r] = __builtin_amdgcn_exp2f(ss[kb][r]);
        bs += e[r];
      }
      bs += __shfl_xor(bs, 32);
      lsum += bs;
      unsigned p[8];
#pragma unroll
      for (int i = 0; i < 8; ++i) p[i] = pk2bf(e[2 * i + 1], e[2 * i]);

#pragma unroll
      for (int sub = 0; sub < 2; ++sub) {
        unsigned pl0 = p[sub * 4 + 0], pl1 = p[sub * 4 + 1];
        unsigned ph0 = p[sub * 4 + 2], ph1 = p[sub * 4 + 3];
        unsigned rec0 = __shfl_xor((int)(h ? pl0 : ph0), 32);
        unsigned rec1 = __shfl_xor((int)(h ? pl1 : ph1), 32);
        union { unsigned u[4]; bf16x8 v; } pf;
        pf.u[0] = h ? rec0 : pl0;
        pf.u[1] = h ? rec1 : pl1;
        pf.u[2] = h ? ph0 : rec0;
        pf.u[3] = h ? ph1 : rec1;
#pragma unroll
        for (int db = 0; db < 2; ++db) {
          bf16x8 vf = *reinterpret_cast<const bf16x8*>(
              Vs + (db * 32 + l31) * 128 + (((kb * 4 + sub * 2 + h) ^ s7) * 8));
          oacc[db] = __builtin_amdgcn_mfma_f32_32x32x16_bf16(vf, pf.v, oacc[db], 0, 0, 0);
        }
      }
    }
    __syncthreads();
  }

  // finalize: lane holds O[q=w*32+l31][d = db*32 + (r&3)+8*(r>>2)+4*h]
  float inv = 1.0f / lsum;
  unsigned short* ob = O + (size_t)(tq0 + w * 32 + l31) * 1024 + hoff;
#pragma unroll
  for (int db = 0; db < 2; ++db)
#pragma unroll
    for (int rg = 0; rg < 4; ++rg) {
      int d0 = db * 32 + rg * 8 + h * 4;
      uint2 ov;
      ov.x = pk2bf(oacc[db][rg * 4 + 1] * inv, oacc[db][rg * 4 + 0] * inv);
      ov.y = pk2bf(oacc[db][rg * 4 + 3] * inv, oacc[db][rg * 4 + 2] * inv);
      *reinterpret_cast<uint2*>(ob + d0) = ov;
    }
}

// ---------------- launch ---------------------------------------------------
extern "C" void kernel_launch(void* const* d_in, const int* in_sizes, int n_in,
                              void* d_out, int out_size, void* d_ws, size_t ws_size,
                              hipStream_t stream) {
  const float* h    = (const float*)d_in[0];
  const float* Wq   = (const float*)d_in[1];
  const float* bq   = (const float*)d_in[2];
  const float* Wk   = (const float*)d_in[3];
  const float* bk   = (const float*)d_in[4];
  const float* Wv   = (const float*)d_in[5];
  const float* bv   = (const float*)d_in[6];
  const float* Wo   = (const float*)d_in[7];
  const float* bo   = (const float*)d_in[8];
  const float* ln_w = (const float*)d_in[9];
  const float* ln_b = (const float*)d_in[10];
  float* out = (float*)d_out;

  unsigned short* ws = (unsigned short*)d_ws;
  const size_t WSZ = (size_t)1 << 20;
  unsigned short* Wcat = ws;                       // 4M shorts: Wq|Wk|Wv|Wo
  unsigned short* hn   = Wcat + 4 * WSZ;           // [4096][1024]
  unsigned short* QKb  = hn + (size_t)TOKENS * D_MODEL;        // [4096][2048]
  unsigned short* VtG  = QKb + (size_t)TOKENS * 2048;          // [1024][4096]
  unsigned short* Obuf = VtG + (size_t)D_MODEL * TOKENS;       // [4096][1024]

  prep_kernel<<<8192, 256, 0, stream>>>(h, Wq, Wk, Wv, Wo, ln_w, ln_b, Wcat, hn);

  gemm_qkv_kernel<<<dim3(24, 32), 256, 0, stream>>>(hn, Wcat, bq, bk, bv, QKb, VtG);

  attn_kernel<<<dim3(N_HEADS, SEQ / 64, BATCH), 128, 0, stream>>>(QKb, VtG, Obuf);

  gemm_out_kernel<<<dim3(16, 32), 256, 0, stream>>>(Obuf, Wcat + 3 * WSZ, bo, h, out);
}